// Round 1
// baseline (534.623 us; speedup 1.0000x reference)
//
#include <hip/hip_runtime.h>
#include <cmath>

// GraphSAGE forward for MI355X (gfx950).
// Pipeline: H1 = x@W1+b1 ; A1 = meanagg(H1) ; H2 = relu(A1)@W2+b2 ;
//           A2 = meanagg(H2) ; H3 = relu(A2)@Wp1+bp1 ; H4 = H3@Wp2+bp2 ;
//           out = log_softmax(H4)
// meanagg: out[s] = (1/deg(s)) * sum_{(s,t) in E} h[t],  deg(s)=#out-edges of s.

__global__ void count_deg_kernel(const int* __restrict__ src, int* __restrict__ deg, int E) {
    int gid = blockIdx.x * blockDim.x + threadIdx.x;
    if (gid < E) atomicAdd(&deg[src[gid]], 1);
}

// Y[n x KOUT] = (optional relu)(X[n x 64]) @ W[64 x KOUT] + b
// blockDim = ROWS*KOUT (multiple of 64). One output element per thread.
template <int KOUT, int ROWS, bool RELU_IN>
__global__ __launch_bounds__(KOUT * ROWS) void gemm64_kernel(
    const float* __restrict__ X, const float* __restrict__ W,
    const float* __restrict__ b, float* __restrict__ Y, int n) {
    __shared__ float xs[ROWS][64];
    __shared__ float ws[64][KOUT];
    constexpr int NT = KOUT * ROWS;
    const int tid  = threadIdx.x;
    const int row0 = blockIdx.x * ROWS;

    // Stage W (64*KOUT) into LDS — coalesced, L2-hot across blocks.
    for (int i = tid; i < 64 * KOUT; i += NT)
        ws[i / KOUT][i % KOUT] = W[i];
    // Stage ROWS input rows into LDS (apply input relu here if requested).
    for (int i = tid; i < ROWS * 64; i += NT) {
        int rr = row0 + (i >> 6);
        float v = (rr < n) ? X[(size_t)row0 * 64 + i] : 0.f;
        if (RELU_IN) v = fmaxf(v, 0.f);
        xs[i >> 6][i & 63] = v;
    }
    __syncthreads();

    const int r = tid / KOUT;
    const int c = tid % KOUT;
    float acc = b[c];
#pragma unroll
    for (int k = 0; k < 64; ++k)
        acc = fmaf(xs[r][k], ws[k][c], acc);   // xs broadcast; ws stride-1 -> no conflicts

    const int row = row0 + r;
    if (row < n) Y[(size_t)row * KOUT + c] = acc;
}

// One wave per edge: lane d handles dim d. out[s][d] += H[t][d] / deg[s].
__global__ void scatter_mean_kernel(const float* __restrict__ H,
                                    const int* __restrict__ src,
                                    const int* __restrict__ dst,
                                    const int* __restrict__ deg,
                                    float* __restrict__ out, int E) {
    int gid = blockIdx.x * blockDim.x + threadIdx.x;
    int e = gid >> 6;
    if (e >= E) return;
    int d = gid & 63;
    int s = src[e];                       // wave-uniform scalar load
    int t = dst[e];
    float w = 1.0f / (float)deg[s];
    atomicAdd(&out[(size_t)s * 64 + d], H[(size_t)t * 64 + d] * w);
}

// In-place row log-softmax, rows of 40. One wave per row.
__global__ void log_softmax40_kernel(float* __restrict__ Y, int n) {
    int gid  = blockIdx.x * blockDim.x + threadIdx.x;
    int row  = gid >> 6;
    int lane = threadIdx.x & 63;
    if (row >= n) return;
    float v = (lane < 40) ? Y[(size_t)row * 40 + lane] : -INFINITY;
    float m = v;
#pragma unroll
    for (int o = 32; o; o >>= 1) m = fmaxf(m, __shfl_xor(m, o));
    float e = (lane < 40) ? expf(v - m) : 0.f;
    float s = e;
#pragma unroll
    for (int o = 32; o; o >>= 1) s += __shfl_xor(s, o);
    float ls = logf(s);
    if (lane < 40) Y[(size_t)row * 40 + lane] = v - m - ls;
}

extern "C" void kernel_launch(void* const* d_in, const int* in_sizes, int n_in,
                              void* d_out, int out_size, void* d_ws, size_t ws_size,
                              hipStream_t stream) {
    const float* x   = (const float*)d_in[0];
    const int*   ei  = (const int*)d_in[1];
    const float* W1  = (const float*)d_in[2];
    const float* b1  = (const float*)d_in[3];
    const float* W2  = (const float*)d_in[4];
    const float* b2  = (const float*)d_in[5];
    const float* Wp1 = (const float*)d_in[6];
    const float* bp1 = (const float*)d_in[7];
    const float* Wp2 = (const float*)d_in[8];
    const float* bp2 = (const float*)d_in[9];
    float* out = (float*)d_out;

    const int N = in_sizes[0] / 64;
    const int E = in_sizes[1] / 2;
    const int* src = ei;        // edge_index[0, :]
    const int* dst = ei + E;    // edge_index[1, :]

    // Workspace layout (all zeroed where needed, every call).
    char*  wsb = (char*)d_ws;
    size_t off = 0;
    int*   deg = (int*)(wsb + off);  off += ((size_t)N * 4 + 511) & ~(size_t)511;
    float* B1  = (float*)(wsb + off); off += (size_t)N * 64 * 4;
    float* B2  = (float*)(wsb + off); off += (size_t)N * 64 * 4;
    (void)ws_size; (void)n_in; (void)out_size;

    const int edgeBlocks  = (E + 255) / 256;
    const int edgeWaveBlk = (int)(((size_t)E * 64 + 255) / 256);
    const int gemmBlocks  = (N + 3) / 4;

    // deg(src)
    hipMemsetAsync(deg, 0, (size_t)N * 4, stream);
    count_deg_kernel<<<edgeBlocks, 256, 0, stream>>>(src, deg, E);

    // Layer 1
    gemm64_kernel<64, 4, false><<<gemmBlocks, 256, 0, stream>>>(x, W1, b1, B1, N);
    hipMemsetAsync(B2, 0, (size_t)N * 64 * 4, stream);
    scatter_mean_kernel<<<edgeWaveBlk, 256, 0, stream>>>(B1, src, dst, deg, B2, E);

    // Layer 2 (relu fused into GEMM input read)
    gemm64_kernel<64, 4, true><<<gemmBlocks, 256, 0, stream>>>(B2, W2, b2, B1, N);
    hipMemsetAsync(B2, 0, (size_t)N * 64 * 4, stream);
    scatter_mean_kernel<<<edgeWaveBlk, 256, 0, stream>>>(B1, src, dst, deg, B2, E);

    // post_mp
    gemm64_kernel<64, 4, true><<<gemmBlocks, 256, 0, stream>>>(B2, Wp1, bp1, B1, N);
    gemm64_kernel<40, 8, false><<<(N + 7) / 8, 320, 0, stream>>>(B1, Wp2, bp2, out, N);

    // log_softmax in place on d_out
    log_softmax40_kernel<<<(int)(((size_t)N * 64 + 255) / 256), 256, 0, stream>>>(out, N);
}

// Round 2
// 303.573 us; speedup vs baseline: 1.7611x; 1.7611x over previous
//
#include <hip/hip_runtime.h>
#include <cmath>

// GraphSAGE forward for MI355X (gfx950).
// R2: CSR-gather mean-aggregation (replaces atomic scatter).
// Pipeline: build CSR once; H1 = x@W1+b1 ; A1 = gather_mean(H1) ;
//           H2 = relu(A1)@W2+b2 ; A2 = gather_mean(H2) ;
//           H3 = relu(A2)@Wp1+bp1 ; H4 = H3@Wp2+bp2 ; out = log_softmax(H4)

#define SCAN_BS 512

__global__ void count_deg_kernel(const int* __restrict__ src, int* __restrict__ deg, int E) {
    int gid = blockIdx.x * blockDim.x + threadIdx.x;
    if (gid < E) atomicAdd(&deg[src[gid]], 1);
}

// --- 3-phase exclusive scan of deg[N] -> rowptr[N+1] ---
__global__ __launch_bounds__(SCAN_BS) void scan1_kernel(const int* __restrict__ deg,
                                                        int* __restrict__ chunkScan,
                                                        int* __restrict__ blockSums, int N) {
    __shared__ int tmp[SCAN_BS];
    int gid = blockIdx.x * SCAN_BS + threadIdx.x;
    int v = (gid < N) ? deg[gid] : 0;
    tmp[threadIdx.x] = v;
    __syncthreads();
    for (int off = 1; off < SCAN_BS; off <<= 1) {
        int add = (threadIdx.x >= off) ? tmp[threadIdx.x - off] : 0;
        __syncthreads();
        tmp[threadIdx.x] += add;
        __syncthreads();
    }
    if (gid < N) chunkScan[gid] = tmp[threadIdx.x] - v;            // exclusive within chunk
    if (threadIdx.x == SCAN_BS - 1) blockSums[blockIdx.x] = tmp[threadIdx.x];
}

__global__ __launch_bounds__(SCAN_BS) void scan2_kernel(int* __restrict__ blockSums, int nb) {
    __shared__ int tmp[SCAN_BS];
    int v = (threadIdx.x < nb) ? blockSums[threadIdx.x] : 0;
    tmp[threadIdx.x] = v;
    __syncthreads();
    for (int off = 1; off < SCAN_BS; off <<= 1) {
        int add = (threadIdx.x >= off) ? tmp[threadIdx.x - off] : 0;
        __syncthreads();
        tmp[threadIdx.x] += add;
        __syncthreads();
    }
    if (threadIdx.x < nb) blockSums[threadIdx.x] = tmp[threadIdx.x] - v;  // exclusive
}

__global__ void scan3_kernel(const int* __restrict__ chunkScan, const int* __restrict__ blockSums,
                             int* __restrict__ rowptr, int N, int E) {
    int gid = blockIdx.x * blockDim.x + threadIdx.x;
    if (gid < N) rowptr[gid] = chunkScan[gid] + blockSums[gid / SCAN_BS];
    if (gid == 0) rowptr[N] = E;
}

// Scatter edges into CSR column array (order within a segment is arbitrary).
__global__ void build_col_kernel(const int* __restrict__ src, const int* __restrict__ dst,
                                 int* __restrict__ cursor, int* __restrict__ col, int E) {
    int e = blockIdx.x * blockDim.x + threadIdx.x;
    if (e < E) {
        int pos = atomicAdd(&cursor[src[e]], 1);
        col[pos] = dst[e];
    }
}

// One wave per node, lane d = feature dim d. out[s] = mean over CSR neighbors of H[t].
__global__ __launch_bounds__(256) void gather_mean_kernel(const float* __restrict__ H,
                                                          const int* __restrict__ rowptr,
                                                          const int* __restrict__ col,
                                                          float* __restrict__ out, int N) {
    int node = blockIdx.x * (blockDim.x >> 6) + (threadIdx.x >> 6);
    int lane = threadIdx.x & 63;
    if (node >= N) return;
    int beg = rowptr[node];
    int end = rowptr[node + 1];
    float acc = 0.f;
    int e = beg;
    for (; e + 4 <= end; e += 4) {            // 4 independent gathers in flight
        int t0 = col[e], t1 = col[e + 1], t2 = col[e + 2], t3 = col[e + 3];
        float v0 = H[(size_t)t0 * 64 + lane];
        float v1 = H[(size_t)t1 * 64 + lane];
        float v2 = H[(size_t)t2 * 64 + lane];
        float v3 = H[(size_t)t3 * 64 + lane];
        acc += (v0 + v1) + (v2 + v3);
    }
    for (; e < end; ++e) acc += H[(size_t)col[e] * 64 + lane];
    float inv = (end > beg) ? 1.f / (float)(end - beg) : 0.f;
    out[(size_t)node * 64 + lane] = acc * inv;
}

// Y[n x KOUT] = (optional relu)(X[n x 64]) @ W[64 x KOUT] + b
template <int KOUT, int ROWS, bool RELU_IN>
__global__ __launch_bounds__(KOUT * ROWS) void gemm64_kernel(
    const float* __restrict__ X, const float* __restrict__ W,
    const float* __restrict__ b, float* __restrict__ Y, int n) {
    __shared__ float xs[ROWS][64];
    __shared__ float ws[64][KOUT];
    constexpr int NT = KOUT * ROWS;
    const int tid  = threadIdx.x;
    const int row0 = blockIdx.x * ROWS;

    for (int i = tid; i < 64 * KOUT; i += NT)
        ws[i / KOUT][i % KOUT] = W[i];
    for (int i = tid; i < ROWS * 64; i += NT) {
        int rr = row0 + (i >> 6);
        float v = (rr < n) ? X[(size_t)row0 * 64 + i] : 0.f;
        if (RELU_IN) v = fmaxf(v, 0.f);
        xs[i >> 6][i & 63] = v;
    }
    __syncthreads();

    const int r = tid / KOUT;
    const int c = tid % KOUT;
    float acc = b[c];
#pragma unroll
    for (int k = 0; k < 64; ++k)
        acc = fmaf(xs[r][k], ws[k][c], acc);

    const int row = row0 + r;
    if (row < n) Y[(size_t)row * KOUT + c] = acc;
}

// In-place row log-softmax, rows of 40. One wave per row.
__global__ void log_softmax40_kernel(float* __restrict__ Y, int n) {
    int gid  = blockIdx.x * blockDim.x + threadIdx.x;
    int row  = gid >> 6;
    int lane = threadIdx.x & 63;
    if (row >= n) return;
    float v = (lane < 40) ? Y[(size_t)row * 40 + lane] : -INFINITY;
    float m = v;
#pragma unroll
    for (int o = 32; o; o >>= 1) m = fmaxf(m, __shfl_xor(m, o));
    float e = (lane < 40) ? expf(v - m) : 0.f;
    float s = e;
#pragma unroll
    for (int o = 32; o; o >>= 1) s += __shfl_xor(s, o);
    float ls = logf(s);
    if (lane < 40) Y[(size_t)row * 40 + lane] = v - m - ls;
}

extern "C" void kernel_launch(void* const* d_in, const int* in_sizes, int n_in,
                              void* d_out, int out_size, void* d_ws, size_t ws_size,
                              hipStream_t stream) {
    const float* x   = (const float*)d_in[0];
    const int*   ei  = (const int*)d_in[1];
    const float* W1  = (const float*)d_in[2];
    const float* b1  = (const float*)d_in[3];
    const float* W2  = (const float*)d_in[4];
    const float* b2  = (const float*)d_in[5];
    const float* Wp1 = (const float*)d_in[6];
    const float* bp1 = (const float*)d_in[7];
    const float* Wp2 = (const float*)d_in[8];
    const float* bp2 = (const float*)d_in[9];
    float* out = (float*)d_out;

    const int N = in_sizes[0] / 64;
    const int E = in_sizes[1] / 2;
    const int* src = ei;        // edge_index[0, :]
    const int* dst = ei + E;    // edge_index[1, :]

    // Workspace layout
    char*  wsb = (char*)d_ws;
    size_t off = 0;
    auto alloc = [&](size_t bytes) { void* p = wsb + off; off += (bytes + 511) & ~(size_t)511; return p; };
    int*   deg       = (int*)alloc((size_t)N * 4);
    int*   rowptr    = (int*)alloc((size_t)(N + 1) * 4);
    int*   cursor    = (int*)alloc((size_t)N * 4);
    int*   chunkScan = (int*)alloc((size_t)N * 4);
    int*   blockSums = (int*)alloc((size_t)SCAN_BS * 4);
    int*   col       = (int*)alloc((size_t)E * 4);
    float* B1        = (float*)alloc((size_t)N * 64 * 4);
    float* B2        = (float*)alloc((size_t)N * 64 * 4);
    (void)ws_size; (void)n_in; (void)out_size;

    const int edgeBlocks = (E + 255) / 256;
    const int gemmBlocks = (N + 3) / 4;
    const int scanBlocks = (N + SCAN_BS - 1) / SCAN_BS;
    const int nodeBlocks = (N + 3) / 4;   // 4 waves/block in gather

    // --- Build CSR (once; reused by both aggregations) ---
    hipMemsetAsync(deg, 0, (size_t)N * 4, stream);
    count_deg_kernel<<<edgeBlocks, 256, 0, stream>>>(src, deg, E);
    scan1_kernel<<<scanBlocks, SCAN_BS, 0, stream>>>(deg, chunkScan, blockSums, N);
    scan2_kernel<<<1, SCAN_BS, 0, stream>>>(blockSums, scanBlocks);
    scan3_kernel<<<(N + 255) / 256, 256, 0, stream>>>(chunkScan, blockSums, rowptr, N, E);
    hipMemcpyAsync(cursor, rowptr, (size_t)N * 4, hipMemcpyDeviceToDevice, stream);
    build_col_kernel<<<edgeBlocks, 256, 0, stream>>>(src, dst, cursor, col, E);

    // --- Layer 1 ---
    gemm64_kernel<64, 4, false><<<gemmBlocks, 256, 0, stream>>>(x, W1, b1, B1, N);
    gather_mean_kernel<<<nodeBlocks, 256, 0, stream>>>(B1, rowptr, col, B2, N);

    // --- Layer 2 (relu fused into GEMM input read) ---
    gemm64_kernel<64, 4, true><<<gemmBlocks, 256, 0, stream>>>(B2, W2, b2, B1, N);
    gather_mean_kernel<<<nodeBlocks, 256, 0, stream>>>(B1, rowptr, col, B2, N);

    // --- post_mp ---
    gemm64_kernel<64, 4, true><<<gemmBlocks, 256, 0, stream>>>(B2, Wp1, bp1, B1, N);
    gemm64_kernel<40, 8, false><<<(N + 7) / 8, 320, 0, stream>>>(B1, Wp2, bp2, out, N);

    log_softmax40_kernel<<<(int)(((size_t)N * 64 + 255) / 256), 256, 0, stream>>>(out, N);
}

// Round 3
// 264.582 us; speedup vs baseline: 2.0206x; 1.1474x over previous
//
#include <hip/hip_runtime.h>
#include <cmath>

// GraphSAGE forward for MI355X (gfx950).
// R3: XCD-partitioned CSR build (src-range per XCD -> no cross-XCD line
//     ping-pong), u16 col array, register-W GEMM with broadcast ds_read_b128.

#define SCAN_BS 512
#define NXCD 8

// --- Partitioned degree count: group g handles src in [g*chunk, (g+1)*chunk) ---
__global__ __launch_bounds__(256) void count_deg_part(const int* __restrict__ src,
                                                      int* __restrict__ deg, int E, int N) {
    int g    = blockIdx.x & (NXCD - 1);          // presumed XCD id (round-robin)
    int bpg  = blockIdx.x >> 3;                  // block index within group
    int nbpg = gridDim.x >> 3;                   // blocks per group
    int chunk = (N + NXCD - 1) / NXCD;
    int lo = g * chunk;
    int hi = min(N, lo + chunk);
    for (int e = bpg * 256 + threadIdx.x; e < E; e += nbpg * 256) {
        int s = src[e];
        if (s >= lo && s < hi) atomicAdd(&deg[s], 1);
    }
}

// --- 3-phase exclusive scan of deg[N] -> rowptr[N+1] ---
__global__ __launch_bounds__(SCAN_BS) void scan1_kernel(const int* __restrict__ deg,
                                                        int* __restrict__ chunkScan,
                                                        int* __restrict__ blockSums, int N) {
    __shared__ int tmp[SCAN_BS];
    int gid = blockIdx.x * SCAN_BS + threadIdx.x;
    int v = (gid < N) ? deg[gid] : 0;
    tmp[threadIdx.x] = v;
    __syncthreads();
    for (int off = 1; off < SCAN_BS; off <<= 1) {
        int add = (threadIdx.x >= off) ? tmp[threadIdx.x - off] : 0;
        __syncthreads();
        tmp[threadIdx.x] += add;
        __syncthreads();
    }
    if (gid < N) chunkScan[gid] = tmp[threadIdx.x] - v;
    if (threadIdx.x == SCAN_BS - 1) blockSums[blockIdx.x] = tmp[threadIdx.x];
}

__global__ __launch_bounds__(SCAN_BS) void scan2_kernel(int* __restrict__ blockSums, int nb) {
    __shared__ int tmp[SCAN_BS];
    int v = (threadIdx.x < nb) ? blockSums[threadIdx.x] : 0;
    tmp[threadIdx.x] = v;
    __syncthreads();
    for (int off = 1; off < SCAN_BS; off <<= 1) {
        int add = (threadIdx.x >= off) ? tmp[threadIdx.x - off] : 0;
        __syncthreads();
        tmp[threadIdx.x] += add;
        __syncthreads();
    }
    if (threadIdx.x < nb) blockSums[threadIdx.x] = tmp[threadIdx.x] - v;
}

__global__ void scan3_kernel(const int* __restrict__ chunkScan, const int* __restrict__ blockSums,
                             int* __restrict__ rowptr, int N, int E) {
    int gid = blockIdx.x * blockDim.x + threadIdx.x;
    if (gid < N) rowptr[gid] = chunkScan[gid] + blockSums[gid / SCAN_BS];
    if (gid == 0) rowptr[N] = E;
}

// --- Partitioned CSR column fill (u16): each src-range owned by one XCD ---
__global__ __launch_bounds__(256) void build_col_part(const int* __restrict__ src,
                                                      const int* __restrict__ dst,
                                                      int* __restrict__ cursor,
                                                      unsigned short* __restrict__ col,
                                                      int E, int N) {
    int g    = blockIdx.x & (NXCD - 1);
    int bpg  = blockIdx.x >> 3;
    int nbpg = gridDim.x >> 3;
    int chunk = (N + NXCD - 1) / NXCD;
    int lo = g * chunk;
    int hi = min(N, lo + chunk);
    for (int e = bpg * 256 + threadIdx.x; e < E; e += nbpg * 256) {
        int s = src[e];
        if (s >= lo && s < hi) {
            int pos = atomicAdd(&cursor[s], 1);
            col[pos] = (unsigned short)dst[e];
        }
    }
}

// One wave per node, lane d = feature dim d. out[s] = mean over CSR neighbors of H[t].
__global__ __launch_bounds__(256) void gather_mean_kernel(const float* __restrict__ H,
                                                          const int* __restrict__ rowptr,
                                                          const unsigned short* __restrict__ col,
                                                          float* __restrict__ out, int N) {
    int node = blockIdx.x * (blockDim.x >> 6) + (threadIdx.x >> 6);
    int lane = threadIdx.x & 63;
    if (node >= N) return;
    int beg = rowptr[node];
    int end = rowptr[node + 1];
    float acc = 0.f;
    int e = beg;
    for (; e + 4 <= end; e += 4) {
        int t0 = col[e], t1 = col[e + 1], t2 = col[e + 2], t3 = col[e + 3];
        float v0 = H[(size_t)t0 * 64 + lane];
        float v1 = H[(size_t)t1 * 64 + lane];
        float v2 = H[(size_t)t2 * 64 + lane];
        float v3 = H[(size_t)t3 * 64 + lane];
        acc += (v0 + v1) + (v2 + v3);
    }
    for (; e < end; ++e) acc += H[(size_t)col[e] * 64 + lane];
    float inv = (end > beg) ? 1.f / (float)(end - beg) : 0.f;
    out[(size_t)node * 64 + lane] = acc * inv;
}

// Y[n x KOUT] = (optional relu)(X[n x 64]) @ W[64 x KOUT] + b
// Block = 256 thr (4 waves), 32 rows/block (8 rows/wave). W column in VGPRs;
// X rows staged in LDS, consumed via broadcast ds_read_b128 (conflict-free).
template <int KOUT, bool RELU_IN>
__global__ __launch_bounds__(256) void gemm_fast(const float* __restrict__ X,
                                                 const float* __restrict__ W,
                                                 const float* __restrict__ b,
                                                 float* __restrict__ Y, int n) {
    __shared__ float xs[32][64];
    const int tid  = threadIdx.x;
    const int lane = tid & 63;
    const int wv   = tid >> 6;
    const int row0 = blockIdx.x * 32;

    // Stage 32 input rows (coalesced 8KB), fused input relu.
    for (int i = tid; i < 32 * 64; i += 256) {
        int rr = row0 + (i >> 6);
        float v = (rr < n) ? X[(size_t)row0 * 64 + i] : 0.f;
        if (RELU_IN) v = fmaxf(v, 0.f);
        xs[i >> 6][i & 63] = v;
    }

    // W column for this lane -> registers (coalesced per-k, L2-hot).
    float w[64];
#pragma unroll
    for (int k = 0; k < 64; ++k)
        w[k] = (lane < KOUT) ? W[k * KOUT + lane] : 0.f;
    const float bias = (lane < KOUT) ? b[lane] : 0.f;
    __syncthreads();

#pragma unroll
    for (int r8 = 0; r8 < 8; ++r8) {
        const int r = wv * 8 + r8;
        float a0 = 0.f, a1 = 0.f, a2 = 0.f, a3 = 0.f;
#pragma unroll
        for (int k4 = 0; k4 < 16; ++k4) {
            float4 xv = *(const float4*)&xs[r][k4 * 4];   // broadcast read
            a0 = fmaf(xv.x, w[4 * k4 + 0], a0);
            a1 = fmaf(xv.y, w[4 * k4 + 1], a1);
            a2 = fmaf(xv.z, w[4 * k4 + 2], a2);
            a3 = fmaf(xv.w, w[4 * k4 + 3], a3);
        }
        float acc = bias + ((a0 + a1) + (a2 + a3));
        const int grow = row0 + r;
        if (grow < n && lane < KOUT) Y[(size_t)grow * KOUT + lane] = acc;
    }
}

// In-place row log-softmax, rows of 40. One wave per row.
__global__ void log_softmax40_kernel(float* __restrict__ Y, int n) {
    int gid  = blockIdx.x * blockDim.x + threadIdx.x;
    int row  = gid >> 6;
    int lane = threadIdx.x & 63;
    if (row >= n) return;
    float v = (lane < 40) ? Y[(size_t)row * 40 + lane] : -INFINITY;
    float m = v;
#pragma unroll
    for (int o = 32; o; o >>= 1) m = fmaxf(m, __shfl_xor(m, o));
    float e = (lane < 40) ? expf(v - m) : 0.f;
    float s = e;
#pragma unroll
    for (int o = 32; o; o >>= 1) s += __shfl_xor(s, o);
    float ls = logf(s);
    if (lane < 40) Y[(size_t)row * 40 + lane] = v - m - ls;
}

extern "C" void kernel_launch(void* const* d_in, const int* in_sizes, int n_in,
                              void* d_out, int out_size, void* d_ws, size_t ws_size,
                              hipStream_t stream) {
    const float* x   = (const float*)d_in[0];
    const int*   ei  = (const int*)d_in[1];
    const float* W1  = (const float*)d_in[2];
    const float* b1  = (const float*)d_in[3];
    const float* W2  = (const float*)d_in[4];
    const float* b2  = (const float*)d_in[5];
    const float* Wp1 = (const float*)d_in[6];
    const float* bp1 = (const float*)d_in[7];
    const float* Wp2 = (const float*)d_in[8];
    const float* bp2 = (const float*)d_in[9];
    float* out = (float*)d_out;

    const int N = in_sizes[0] / 64;
    const int E = in_sizes[1] / 2;
    const int* src = ei;        // edge_index[0, :]
    const int* dst = ei + E;    // edge_index[1, :]

    // Workspace layout
    char*  wsb = (char*)d_ws;
    size_t off = 0;
    auto alloc = [&](size_t bytes) { void* p = wsb + off; off += (bytes + 511) & ~(size_t)511; return p; };
    int*            deg       = (int*)alloc((size_t)N * 4);
    int*            rowptr    = (int*)alloc((size_t)(N + 1) * 4);
    int*            cursor    = (int*)alloc((size_t)N * 4);
    int*            chunkScan = (int*)alloc((size_t)N * 4);
    int*            blockSums = (int*)alloc((size_t)SCAN_BS * 4);
    unsigned short* col       = (unsigned short*)alloc((size_t)E * 2);
    float*          B1        = (float*)alloc((size_t)N * 64 * 4);
    float*          B2        = (float*)alloc((size_t)N * 64 * 4);
    (void)ws_size; (void)n_in; (void)out_size;

    const int scanBlocks = (N + SCAN_BS - 1) / SCAN_BS;
    const int gemmBlocks = (N + 31) / 32;
    const int nodeBlocks = (N + 3) / 4;      // 4 waves/block in gather
    const int partBlocks = 1024;             // 128 blocks per XCD group

    // --- Build CSR (once; reused by both aggregations) ---
    hipMemsetAsync(deg, 0, (size_t)N * 4, stream);
    count_deg_part<<<partBlocks, 256, 0, stream>>>(src, deg, E, N);
    scan1_kernel<<<scanBlocks, SCAN_BS, 0, stream>>>(deg, chunkScan, blockSums, N);
    scan2_kernel<<<1, SCAN_BS, 0, stream>>>(blockSums, scanBlocks);
    scan3_kernel<<<(N + 255) / 256, 256, 0, stream>>>(chunkScan, blockSums, rowptr, N, E);
    hipMemcpyAsync(cursor, rowptr, (size_t)N * 4, hipMemcpyDeviceToDevice, stream);
    build_col_part<<<partBlocks, 256, 0, stream>>>(src, dst, cursor, col, E, N);

    // --- Layer 1 ---
    gemm_fast<64, false><<<gemmBlocks, 256, 0, stream>>>(x, W1, b1, B1, N);
    gather_mean_kernel<<<nodeBlocks, 256, 0, stream>>>(B1, rowptr, col, B2, N);

    // --- Layer 2 (relu fused into GEMM input read) ---
    gemm_fast<64, true><<<gemmBlocks, 256, 0, stream>>>(B2, W2, b2, B1, N);
    gather_mean_kernel<<<nodeBlocks, 256, 0, stream>>>(B1, rowptr, col, B2, N);

    // --- post_mp ---
    gemm_fast<64, true><<<gemmBlocks, 256, 0, stream>>>(B2, Wp1, bp1, B1, N);
    gemm_fast<40, false><<<gemmBlocks, 256, 0, stream>>>(B1, Wp2, bp2, out, N);

    log_softmax40_kernel<<<(int)(((size_t)N * 64 + 255) / 256), 256, 0, stream>>>(out, N);
}